// Round 2
// baseline (507.187 us; speedup 1.0000x reference)
//
#include <hip/hip_runtime.h>

#define NSEQ   2000
#define CHUNK  200
#define CPAD   212          // padded row stride (dwords); 212*4=848B, 16B-aligned rows
#define NCHUNK (NSEQ / CHUNK)
#define GATES  40
#define HID    10
#define LOG2E  1.4426950408889634f

__device__ __forceinline__ float rl(float v, int l) {
    return __uint_as_float(__builtin_amdgcn_readlane(__float_as_uint(v), l));
}
// quad_perm broadcast of quad-lane CTRL's value to all 4 lanes of the quad
template <int CTRL>
__device__ __forceinline__ float qb(float v) {
    return __int_as_float(
        __builtin_amdgcn_update_dpp(0, __float_as_int(v), CTRL, 0xF, 0xF, false));
}

// One row's gate pre-activations, written TRANSPOSED into LDS as dst[g*CPAD],
// pre-scaled by m*log2(e) per gate type (g-gates: +2*log2e, i/f/o: -log2e)
__device__ __attribute__((noinline)) void compute_row(
    int r, float* dst,
    const float* __restrict__ x,
    const float* __restrict__ Wmz1, const float* __restrict__ bmz1,
    const float* __restrict__ Wmz2, const float* __restrict__ bmz2,
    const float* __restrict__ Win1, const float* __restrict__ bin1,
    const float* __restrict__ Win2, const float* __restrict__ bin2,
    const float* __restrict__ Wih,
    const float* __restrict__ bih,  const float* __restrict__ bhh)
{
    const float u = x[2 * r];
    const float w = x[2 * r + 1];
    float tr[32];
    {
        float a[32];
#pragma unroll
        for (int i = 0; i < 32; i++) a[i] = fmaxf(fmaf(Wmz1[i], u, bmz1[i]), 0.f);
#pragma unroll
        for (int o = 0; o < 16; o++) {
            float acc = bmz2[o];
#pragma unroll
            for (int k = 0; k < 32; k++) acc = fmaf(Wmz2[o * 32 + k], a[k], acc);
            tr[o] = fmaxf(acc, 0.f);
        }
#pragma unroll
        for (int i = 0; i < 32; i++) a[i] = fmaxf(fmaf(Win1[i], w, bin1[i]), 0.f);
#pragma unroll
        for (int o = 0; o < 16; o++) {
            float acc = bin2[o];
#pragma unroll
            for (int k = 0; k < 32; k++) acc = fmaf(Win2[o * 32 + k], a[k], acc);
            tr[16 + o] = fmaxf(acc, 0.f);
        }
    }
#pragma unroll
    for (int g = 0; g < GATES; g++) {
        float acc = bih[g] + bhh[g];
#pragma unroll
        for (int k = 0; k < 32; k++) acc = fmaf(Wih[g * 32 + k], tr[k], acc);
        const float sc = (g >= 20 && g < 30) ? (2.f * LOG2E) : (-LOG2E);
        dst[g * CPAD] = acc * sc;
    }
}

extern "C" __global__ void __launch_bounds__(512)
msembed_kernel(const float* __restrict__ x,
               const float* __restrict__ Wmz1, const float* __restrict__ bmz1,
               const float* __restrict__ Wmz2, const float* __restrict__ bmz2,
               const float* __restrict__ Win1, const float* __restrict__ bin1,
               const float* __restrict__ Win2, const float* __restrict__ bin2,
               const float* __restrict__ Wih,  const float* __restrict__ Whh,
               const float* __restrict__ bih,  const float* __restrict__ bhh,
               float* __restrict__ out)
{
    // double-buffered transposed xg: [buf][gate][step], 2*40*212*4 = 67,840 B
    __shared__ __align__(16) float s_xg[2][GATES * CPAD];
    const int tid = threadIdx.x;

    // ---- chunk 0 precompute ----
    if (tid < CHUNK)
        compute_row(tid, &s_xg[0][tid], x,
                    Wmz1, bmz1, Wmz2, bmz2, Win1, bin1, Win2, bin2, Wih, bih, bhh);

    // ---- recurrence lane layout: lane 4j+t = gate t (i,f,g,o) of unit j ----
    const int lane = tid & 63;
    const int tpe  = lane & 3;
    int j = lane >> 2;
    if (j > HID - 1) j = HID - 1;        // lanes 40-63 duplicate unit 9 (same values)
    const int grow = tpe * 10 + j;       // pytorch gate row

    // whh pre-scaled by m*log2e so the dot feeds exp2 directly
    const float wsc = (tpe == 2) ? (2.f * LOG2E) : (-LOG2E);
    float whh[HID];
#pragma unroll
    for (int k = 0; k < HID; k++) whh[k] = Whh[grow * HID + k] * wsc;

    // sv = pp*rcp(1+exp2(dot)) + qq:
    //   tpe0 (i): 2*log2e*sigmoid  (pre-scaled for c2-domain)
    //   tpe1/3  : sigmoid
    //   tpe2 (g): tanh
    const float pp = (tpe == 0) ? (2.f * LOG2E) : ((tpe == 2) ? -2.f : 1.f);
    const float qq = (tpe == 2) ? 1.f : 0.f;

    float h = 0.f, c2 = 0.f;             // c2 = 2*log2e * c

    for (int ch = 0; ch < NCHUNK; ch++) {
        __syncthreads();                 // chunk ch's xg now visible
        if (tid < 64) {
            const float* rowp = &s_xg[ch & 1][grow * CPAD];
            float4 cur = *reinterpret_cast<const float4*>(rowp);
            float4 nxt = *reinterpret_cast<const float4*>(rowp + 4);
            float* op = out + ch * CHUNK * HID + j;
            for (int s4 = 0; s4 < CHUNK; s4 += 4) {
                const float4 use = cur;
                cur = nxt;
                // reads into the pad for s4>=192 — garbage, never consumed
                nxt = *reinterpret_cast<const float4*>(rowp + s4 + 8);
                const float xs[4] = {use.x, use.y, use.z, use.w};
#pragma unroll
                for (int t = 0; t < 4; t++) {
                    // broadcast h via readlane -> SGPRs
                    float hs[HID];
#pragma unroll
                    for (int k = 0; k < HID; k++) hs[k] = rl(h, 4 * k);
                    // dot: (xg + W_hh.h) already in m*log2e domain
                    float a0 = xs[t], a1 = hs[9] * whh[9];
#pragma unroll
                    for (int k = 0; k < 4; k++) {
                        a0 = fmaf(hs[2 * k],     whh[2 * k],     a0);
                        a1 = fmaf(hs[2 * k + 1], whh[2 * k + 1], a1);
                    }
                    a0 = fmaf(hs[8], whh[8], a0);
                    const float g  = a0 + a1;
                    const float e  = __builtin_amdgcn_exp2f(g);
                    const float rr = __builtin_amdgcn_rcpf(1.f + e);
                    const float sv = fmaf(pp, rr, qq);
                    // quad gather: i2=2log2e*sig(i), f=sig(f), g=tanh(g), o=sig(o)
                    const float si2 = qb<0x00>(sv);
                    const float sf  = qb<0x55>(sv);
                    const float sg  = qb<0xAA>(sv);
                    const float so  = qb<0xFF>(sv);
                    c2 = fmaf(sf, c2, si2 * sg);
                    const float th = fmaf(
                        -2.f, __builtin_amdgcn_rcpf(1.f + __builtin_amdgcn_exp2f(c2)),
                        1.f);
                    h = so * th;
                    // all lanes store; quad-duplicate lanes write identical values
                    op[t * HID] = h;
                }
                op += 4 * HID;
            }
        } else {
            // waves 1..7: produce chunk ch+1 (overlaps recurrence)
            const int idx = tid - 64;
            const int nc  = ch + 1;
            if (nc < NCHUNK && idx < CHUNK)
                compute_row(nc * CHUNK + idx, &s_xg[nc & 1][idx], x,
                            Wmz1, bmz1, Wmz2, bmz2, Win1, bin1, Win2, bin2,
                            Wih, bih, bhh);
        }
    }
}

extern "C" void kernel_launch(void* const* d_in, const int* in_sizes, int n_in,
                              void* d_out, int out_size, void* d_ws, size_t ws_size,
                              hipStream_t stream)
{
    const float* x    = (const float*)d_in[0];
    const float* Wmz1 = (const float*)d_in[1];
    const float* bmz1 = (const float*)d_in[2];
    const float* Wmz2 = (const float*)d_in[3];
    const float* bmz2 = (const float*)d_in[4];
    const float* Win1 = (const float*)d_in[5];
    const float* bin1 = (const float*)d_in[6];
    const float* Win2 = (const float*)d_in[7];
    const float* bin2 = (const float*)d_in[8];
    const float* Wih  = (const float*)d_in[9];
    const float* Whh  = (const float*)d_in[10];
    const float* bih  = (const float*)d_in[11];
    const float* bhh  = (const float*)d_in[12];
    float* out = (float*)d_out;

    hipLaunchKernelGGL(msembed_kernel, dim3(1), dim3(512), 0, stream,
                       x, Wmz1, bmz1, Wmz2, bmz2, Win1, bin1, Win2, bin2,
                       Wih, Whh, bih, bhh, out);
}